// Round 5
// baseline (274.659 us; speedup 1.0000x reference)
//
#include <hip/hip_runtime.h>
#include <hip/hip_bf16.h>

typedef unsigned short u16;
typedef __attribute__((ext_vector_type(8))) short short8;
typedef __attribute__((ext_vector_type(4))) float f32x4;
typedef __attribute__((ext_vector_type(2))) float f32x2;

#define MFMA16(a, b, c) __builtin_amdgcn_mfma_f32_16x16x32_bf16((a), (b), (c), 0, 0, 0)

__device__ __forceinline__ u16 f2bf(float f) {
  __hip_bfloat16 h = __float2bfloat16(f);
  u16 r;
  __builtin_memcpy(&r, &h, 2);
  return r;
}
__device__ __forceinline__ float bf2f(u16 h) {
  unsigned u = ((unsigned)h) << 16;
  float f;
  __builtin_memcpy(&f, &u, 4);
  return f;
}
__device__ __forceinline__ unsigned pk2(float a, float b) {
  return (unsigned)f2bf(a) | ((unsigned)f2bf(b) << 16);
}
// Load 8 consecutive source elements as bf16 short8 from f32 or bf16 storage.
__device__ __forceinline__ short8 ld8(const void* src, int idx, int isf32) {
  short8 v;
  if (isf32) {
    const float4* s = (const float4*)((const float*)src + idx);
    float4 p0 = s[0], p1 = s[1];
    v[0] = (short)f2bf(p0.x); v[1] = (short)f2bf(p0.y);
    v[2] = (short)f2bf(p0.z); v[3] = (short)f2bf(p0.w);
    v[4] = (short)f2bf(p1.x); v[5] = (short)f2bf(p1.y);
    v[6] = (short)f2bf(p1.z); v[7] = (short)f2bf(p1.w);
  } else {
    v = *(const short8*)((const u16*)src + idx);
  }
  return v;
}
__device__ __forceinline__ float ld1(const void* src, int idx, int isf32) {
  return isf32 ? ((const float*)src)[idx] : bf2f(((const u16*)src)[idx]);
}
// Per-block input-dtype detect (wave-uniform; f32 halves have hot exponents).
__device__ __forceinline__ int detect_isf32(const u16* xw) {
  int lane = threadIdx.x & 63;
  int cnt = 0;
#pragma unroll
  for (int i = 0; i < 16; ++i) {
    u16 w = xw[lane * 16 + i];
    cnt += (((w >> 7) & 0xFF) >= 0xC0) ? 1 : 0;
  }
#pragma unroll
  for (int off = 1; off < 64; off <<= 1) cnt += __shfl_xor(cnt, off, 64);
  return cnt >= 32;
}

// ---------------------------------------------------------------------------
// ws layout (u16 elements):
//   WcT [16][128cout][128cin]  @ 0
//   WqT/WkT/WvT/WpT [128][128] @ 262144/278528/294912/311296
//   Kb  [4][1024][128]         @ 327680
//   Vt  [4][128][1024]         @ 851968
// ---------------------------------------------------------------------------
__global__ void prep_kernel(const void* __restrict__ srk, const void* __restrict__ Wq,
                            const void* __restrict__ Wk, const void* __restrict__ Wv,
                            const void* __restrict__ Wp, const void* __restrict__ x,
                            u16* __restrict__ WcT) {
  const int isf32 = detect_isf32((const u16*)x);
  int gid = blockIdx.x * 256 + threadIdx.x;
  if (gid >= 327680) return;
  int cout = (gid >> 7) & 127, cin = gid & 127;
  float v;
  if (gid < 262144) {
    int mat = gid >> 14;  // (r,s) slice of HWIO sr_kernel
    v = ld1(srk, mat * 16384 + cin * 128 + cout, isf32);
  } else {
    int mat = (gid - 262144) >> 14;
    const void* src = (mat == 0) ? Wq : (mat == 1) ? Wk : (mat == 2) ? Wv : Wp;
    v = ld1(src, cin * 128 + cout, isf32);
  }
  WcT[gid] = f2bf(v);
}

// ---------------------------------------------------------------------------
// Conv (stride-4 4x4 'SAME' == patch GEMM) + bias + LayerNorm + fused K/V.
// Grid 256 WGs x 1024 thr (16 waves). Wave w owns conv tap rs=w (K-split 16).
// Partials in 128 KB f32 LDS; reduce = one row per wave; LN via 64-lane
// shuffles; K/V proj: wave w -> (nt=w>>1, K if even / V if odd).
// ---------------------------------------------------------------------------
__launch_bounds__(1024, 4)
__global__ void conv_ln_kv_kernel(const void* __restrict__ x, const u16* __restrict__ wcT,
                                  const void* __restrict__ sr_bias,
                                  const void* __restrict__ gamma,
                                  const void* __restrict__ beta,
                                  const u16* __restrict__ WkT, const u16* __restrict__ WvT,
                                  u16* __restrict__ Kb, u16* __restrict__ Vt) {
  extern __shared__ char cws[];
  float* Racc = (float*)cws;                    // [16][16][128] f32 = 128 KB
  u16* Xs = (u16*)(cws + 16 * 16 * 128 * 4);    // [16][136] bf16
  const int isf32 = detect_isf32((const u16*)x);
  const int tid = threadIdx.x;
  const int wave = tid >> 6, lane = tid & 63;
  const int quad = lane >> 4, l16 = lane & 15;
  const int g = blockIdx.x;  // rows g*16 .. g*16+15

  const int row = g * 16 + l16;
  const int pb = row >> 10, rem = row & 1023, oh = rem >> 5, ow = rem & 31;
  const int xbase = ((pb * 128 + oh * 4) * 128 + ow * 4) * 128;

  f32x4 acc[8];
#pragma unroll
  for (int i = 0; i < 8; ++i) acc[i] = (f32x4){0.f, 0.f, 0.f, 0.f};

  {  // tap rs = wave (r = wave>>2, s = wave&3)
    const int r = wave >> 2, sc = wave & 3;
    short8 a[4];
#pragma unroll
    for (int kc = 0; kc < 4; ++kc)
      a[kc] = ld8(x, xbase + r * 16384 + sc * 128 + kc * 32 + quad * 8, isf32);
#pragma unroll
    for (int nt = 0; nt < 8; ++nt)
#pragma unroll
      for (int kc = 0; kc < 4; ++kc) {
        short8 bw = *(const short8*)(wcT + wave * 16384 + (nt * 16 + l16) * 128 +
                                     kc * 32 + quad * 8);
        acc[nt] = MFMA16(a[kc], bw, acc[nt]);
      }
  }
  // partials -> LDS
#pragma unroll
  for (int nt = 0; nt < 8; ++nt)
#pragma unroll
    for (int rr = 0; rr < 4; ++rr)
      Racc[(wave * 16 + quad * 4 + rr) * 128 + nt * 16 + l16] = acc[nt][rr];
  __syncthreads();

  // reduce 16 wave-slices; wave owns row `wave`, lane owns 2 cols at lane*2
  {
    const int lrow = wave, c0 = lane * 2;
    f32x2 rsum = (f32x2){0.f, 0.f};
#pragma unroll
    for (int w = 0; w < 16; ++w) {
      f32x2 t = *(const f32x2*)&Racc[(w * 16 + lrow) * 128 + c0];
      rsum[0] += t[0];
      rsum[1] += t[1];
    }
    float v0 = rsum[0] + ld1(sr_bias, c0, isf32);
    float v1 = rsum[1] + ld1(sr_bias, c0 + 1, isf32);
    float sum = v0 + v1, sum2 = v0 * v0 + v1 * v1;
#pragma unroll
    for (int off = 1; off < 64; off <<= 1) {
      sum += __shfl_xor(sum, off, 64);
      sum2 += __shfl_xor(sum2, off, 64);
    }
    const float mu = sum * (1.f / 128.f);
    const float var = sum2 * (1.f / 128.f) - mu * mu;
    const float rinv = rsqrtf(fmaxf(var, 0.f) + 1e-6f);
    float y0 = (v0 - mu) * rinv * ld1(gamma, c0, isf32) + ld1(beta, c0, isf32);
    float y1 = (v1 - mu) * rinv * ld1(gamma, c0 + 1, isf32) + ld1(beta, c0 + 1, isf32);
    *(unsigned*)&Xs[lrow * 136 + c0] = pk2(y0, y1);
  }
  __syncthreads();

  // fused K/V projection: wave w -> nt = w>>1; even waves K, odd waves V
  short8 a2[4];
#pragma unroll
  for (int kc = 0; kc < 4; ++kc)
    a2[kc] = *(const short8*)&Xs[l16 * 136 + kc * 32 + quad * 8];
  const u16* Wm = (wave & 1) ? WvT : WkT;
  const int nt = wave >> 1;
  f32x4 a3 = (f32x4){0.f, 0.f, 0.f, 0.f};
#pragma unroll
  for (int kc = 0; kc < 4; ++kc) {
    short8 bm = *(const short8*)(Wm + (nt * 16 + l16) * 128 + kc * 32 + quad * 8);
    a3 = MFMA16(a2[kc], bm, a3);
  }
#pragma unroll
  for (int rr = 0; rr < 4; ++rr) {
    const int rowg = g * 16 + quad * 4 + rr;
    const int b = rowg >> 10, key = rowg & 1023;
    const int c = nt * 16 + l16;
    if (wave & 1)
      Vt[(b * 128 + c) * 1024 + key] = f2bf(a3[rr]);
    else
      Kb[rowg * 128 + c] = f2bf(a3[rr]);
  }
}

// ---------------------------------------------------------------------------
// Fused attention. Grid 512 x 512 thr (8 waves x 16 q-rows = 128 rows/WG).
// Minimal diff vs the proven round-2 binary: ONLY change is V de-staging.
// V is not copied to LDS; vf A-fragments load per-lane straight from Vt
// (lane=d-row, quad=key-offset). After the XCD swizzle each XCD's resident
// WGs share one batch's K+V = 512 KB, resident in its private 4 MB L2, so
// these are L2 hits whose latency hides under the QK^T MFMAs.
// LDS 54272 -> 35840 B (Ks + per-wave P). __launch_bounds__(512,4) kept
// (known-good codegen; round 2 measured 64 VGPR with MORE live state, so
// the allocator has headroom to stay <=64 -> 4 WGs/CU via the LDS fit).
// K reg-staged with next-chunk prefetch (T14); T1 XCD swizzle; T5 setprio.
// ---------------------------------------------------------------------------
__launch_bounds__(512, 4)
__global__ void attn_kernel(const void* __restrict__ x, const u16* __restrict__ WqT,
                            const u16* __restrict__ WpT, const u16* __restrict__ Kb,
                            const u16* __restrict__ Vt, float* __restrict__ out) {
  extern __shared__ u16 lds[];
  u16* Ks = lds;             // [64][136]  8704 el
  u16* Pp = Ks + 64 * 136;   // [8][1152]  per-wave P scratch (stride 72)
  const int isf32 = detect_isf32((const u16*)x);
  const int tid = threadIdx.x;
  const int wave = tid >> 6, lane = tid & 63;
  const int quad = lane >> 4, l16 = lane & 15;
  const int swz = (blockIdx.x & 7) * 64 + (blockIdx.x >> 3);  // XCD-contiguous
  const int b = swz >> 7;
  const int row0 = (swz & 127) * 128;
  const int wrow = wave * 16;
  u16* Pw = Pp + wave * 1152;   // in-loop P scratch
  u16* Fw = lds + wave * 2176;  // pro/epilogue fixup scratch (overlays Ks+Pp)

  const float qscale = 0.125f * 1.4426950408889634f;  // dh^-0.5 * log2(e)

  // ---- issue chunk-0 K loads first; in flight during whole Q-proj ----
  const int kkey = tid >> 3, kseg = tid & 7;  // K: 64 rows x 8 segs of 16
  const u16* ksrc = Kb + (b * 1024 + kkey) * 128 + kseg * 16;
  uint4 krg0 = *(const uint4*)ksrc;
  uint4 krg1 = *(const uint4*)(ksrc + 8);
  // V fragment base: lane l16 = d-row, quad = key-offset (direct from L2)
  const u16* vbase = Vt + (b * 128 + l16) * 1024 + quad * 8;

  // ---- Q-proj, transposed: D = Q^T[c][q] -> packed b64 -> A-frag reads ----
  short8 qf[2][2];
  {
    short8 xb[4];
#pragma unroll
    for (int kc = 0; kc < 4; ++kc)
      xb[kc] = ld8(x, (b * 16384 + row0 + wrow + l16) * 128 + kc * 32 + quad * 8, isf32);
#pragma unroll
    for (int nt = 0; nt < 8; ++nt) {
      f32x4 qa = (f32x4){0.f, 0.f, 0.f, 0.f};
#pragma unroll
      for (int kc = 0; kc < 4; ++kc) {
        short8 w = *(const short8*)(WqT + (nt * 16 + l16) * 128 + kc * 32 + quad * 8);
        qa = MFMA16(w, xb[kc], qa);  // A=W^T[c][k], B=x[q][k] -> D=Q^T[c][q]
      }
      uint2 pk = {pk2(qa[0] * qscale, qa[1] * qscale), pk2(qa[2] * qscale, qa[3] * qscale)};
      *(uint2*)&Fw[l16 * 136 + nt * 16 + quad * 4] = pk;  // Qst[q][c]
    }
#pragma unroll
    for (int h = 0; h < 2; ++h)
#pragma unroll
      for (int k0 = 0; k0 < 2; ++k0)
        qf[h][k0] = *(const short8*)&Fw[l16 * 136 + h * 64 + k0 * 32 + quad * 8];
  }
  __syncthreads();  // all fixup reads done before Ks/P writes

  f32x4 o[2][4];
#pragma unroll
  for (int h = 0; h < 2; ++h)
#pragma unroll
    for (int nt = 0; nt < 4; ++nt) o[h][nt] = (f32x4){0.f, 0.f, 0.f, 0.f};
  float l[2] = {0.f, 0.f};

  for (int ch = 0; ch < 16; ++ch) {
    {  // commit staged K regs to LDS
      uint4* kd = (uint4*)&Ks[kkey * 136 + kseg * 16];
      kd[0] = krg0;
      kd[1] = krg1;
    }
    __syncthreads();
    if (ch < 15) {  // T14: prefetch next K chunk under this chunk's compute
      krg0 = *(const uint4*)(ksrc + (ch + 1) * 8192);
      krg1 = *(const uint4*)(ksrc + (ch + 1) * 8192 + 8);
    }
#pragma unroll
    for (int h = 0; h < 2; ++h) {
      // ---- S^T per ct (rows=key, cols=q); exp2; packed P[q][key] ----
#pragma unroll
      for (int ct = 0; ct < 4; ++ct) {
        short8 kf0 = *(const short8*)&Ks[(ct * 16 + l16) * 136 + h * 64 + quad * 8];
        short8 kf1 = *(const short8*)&Ks[(ct * 16 + l16) * 136 + h * 64 + 32 + quad * 8];
        f32x4 s0 = (f32x4){0.f, 0.f, 0.f, 0.f};
        s0 = MFMA16(kf0, qf[h][0], s0);  // A=K[key][d], B=Q[q][d] -> S^T
        s0 = MFMA16(kf1, qf[h][1], s0);
        float p0 = exp2f(s0[0]), p1 = exp2f(s0[1]), p2 = exp2f(s0[2]), p3 = exp2f(s0[3]);
        l[h] += (p0 + p1) + (p2 + p3);
        uint2 pka = {pk2(p0, p1), pk2(p2, p3)};
        *(uint2*)&Pw[l16 * 72 + ct * 16 + quad * 4] = pka;
      }
      // ---- O^T += V^T x P  (V fragments direct from L2-resident Vt) ----
      __builtin_amdgcn_s_setprio(1);
#pragma unroll
      for (int kc = 0; kc < 2; ++kc) {
        short8 pf0 = *(const short8*)&Pw[l16 * 72 + kc * 32 + quad * 8];
#pragma unroll
        for (int nt = 0; nt < 4; ++nt) {
          short8 vf = *(const short8*)(vbase + (h * 64 + nt * 16) * 1024 + ch * 64 + kc * 32);
          o[h][nt] = MFMA16(vf, pf0, o[h][nt]);  // A=V^T[d][key], B=P[q][key]
        }
      }
      __builtin_amdgcn_s_setprio(0);
    }
    __syncthreads();
  }

  // ---- softmax denom (quad-reduce) + normalize O^T in registers ----
#pragma unroll
  for (int h = 0; h < 2; ++h) {
    float t = l[h];
    t += __shfl_xor(t, 16, 64);
    t += __shfl_xor(t, 32, 64);
    const float inv = 1.0f / t;
#pragma unroll
    for (int nt = 0; nt < 4; ++nt)
#pragma unroll
      for (int rr = 0; rr < 4; ++rr) o[h][nt][rr] *= inv;
  }

  // ---- epilogue: packed O^T -> LDS (Fw overlays Ks/Pp; loop's final
  //      barrier fences it) -> A-frags -> @Wproj -> f32 out ----
  {
#pragma unroll
    for (int h = 0; h < 2; ++h)
#pragma unroll
      for (int nt = 0; nt < 4; ++nt) {
        uint2 pk = {pk2(o[h][nt][0], o[h][nt][1]), pk2(o[h][nt][2], o[h][nt][3])};
        *(uint2*)&Fw[l16 * 136 + h * 64 + nt * 16 + quad * 4] = pk;  // Ost[q][d]
      }
    short8 of[4];
#pragma unroll
    for (int kc = 0; kc < 4; ++kc)
      of[kc] = *(const short8*)&Fw[l16 * 136 + kc * 32 + quad * 8];
#pragma unroll
    for (int nt = 0; nt < 8; ++nt) {
      f32x4 pa = (f32x4){0.f, 0.f, 0.f, 0.f};
#pragma unroll
      for (int kc = 0; kc < 4; ++kc) {
        short8 w = *(const short8*)(WpT + (nt * 16 + l16) * 128 + kc * 32 + quad * 8);
        pa = MFMA16(of[kc], w, pa);  // A=O[q][d], B=Wp^T[c][d] -> D=[q][c]
      }
#pragma unroll
      for (int rr = 0; rr < 4; ++rr)
        out[(b * 16384 + row0 + wrow + quad * 4 + rr) * 128 + nt * 16 + l16] = pa[rr];
    }
  }
}

// ---------------------------------------------------------------------------
extern "C" void kernel_launch(void* const* d_in, const int* in_sizes, int n_in,
                              void* d_out, int out_size, void* d_ws, size_t ws_size,
                              hipStream_t stream) {
  (void)in_sizes; (void)n_in; (void)out_size; (void)ws_size;
  const void* x = d_in[0];
  const void* Wq = d_in[1];
  const void* Wk = d_in[2];
  const void* Wv = d_in[3];
  const void* Wp = d_in[4];
  const void* srk = d_in[5];
  const void* sbias = d_in[6];
  const void* gamma = d_in[7];
  const void* beta = d_in[8];
  float* out = (float*)d_out;
  u16* ws = (u16*)d_ws;

  u16* WcT = ws;
  u16* WqT = ws + 262144;
  u16* WkT = ws + 278528;
  u16* WvT = ws + 294912;
  u16* WpT = ws + 311296;
  u16* Kb = ws + 327680;
  u16* Vt = ws + 851968;

  prep_kernel<<<dim3(1280), dim3(256), 0, stream>>>(srk, Wq, Wk, Wv, Wp, x, WcT);
  conv_ln_kv_kernel<<<dim3(256), dim3(1024), 16 * 16 * 128 * 4 + 16 * 136 * 2, stream>>>(
      x, WcT, sbias, gamma, beta, WkT, WvT, Kb, Vt);
  attn_kernel<<<dim3(512), dim3(512), (64 * 136 + 8 * 1152) * 2, stream>>>(
      x, WqT, WpT, Kb, Vt, out);
}

// Round 6
// 209.231 us; speedup vs baseline: 1.3127x; 1.3127x over previous
//
#include <hip/hip_runtime.h>
#include <hip/hip_bf16.h>

typedef unsigned short u16;
typedef __attribute__((ext_vector_type(8))) short short8;
typedef __attribute__((ext_vector_type(4))) float f32x4;
typedef __attribute__((ext_vector_type(2))) float f32x2;

#define MFMA16(a, b, c) __builtin_amdgcn_mfma_f32_16x16x32_bf16((a), (b), (c), 0, 0, 0)

__device__ __forceinline__ u16 f2bf(float f) {
  __hip_bfloat16 h = __float2bfloat16(f);
  u16 r;
  __builtin_memcpy(&r, &h, 2);
  return r;
}
__device__ __forceinline__ float bf2f(u16 h) {
  unsigned u = ((unsigned)h) << 16;
  float f;
  __builtin_memcpy(&f, &u, 4);
  return f;
}
// Single-instruction packed f32x2 -> bf16x2 (gfx950 v_cvt_pk_bf16_f32, RNE).
// Replaces ~14 integer ops of __float2bfloat16 emulation per pair.
__device__ __forceinline__ unsigned pk2(float a, float b) {
  unsigned r;
  asm("v_cvt_pk_bf16_f32 %0, %1, %2" : "=v"(r) : "v"(a), "v"(b));
  return r;
}
// Load 8 consecutive source elements as bf16 short8 from f32 or bf16 storage.
__device__ __forceinline__ short8 ld8(const void* src, int idx, int isf32) {
  short8 v;
  if (isf32) {
    const float4* s = (const float4*)((const float*)src + idx);
    float4 p0 = s[0], p1 = s[1];
    unsigned d0 = pk2(p0.x, p0.y), d1 = pk2(p0.z, p0.w);
    unsigned d2 = pk2(p1.x, p1.y), d3 = pk2(p1.z, p1.w);
    uint4 dd = {d0, d1, d2, d3};
    __builtin_memcpy(&v, &dd, 16);
  } else {
    v = *(const short8*)((const u16*)src + idx);
  }
  return v;
}
__device__ __forceinline__ float ld1(const void* src, int idx, int isf32) {
  return isf32 ? ((const float*)src)[idx] : bf2f(((const u16*)src)[idx]);
}
// Per-block input-dtype detect (wave-uniform; f32 halves have hot exponents).
__device__ __forceinline__ int detect_isf32(const u16* xw) {
  int lane = threadIdx.x & 63;
  int cnt = 0;
#pragma unroll
  for (int i = 0; i < 16; ++i) {
    u16 w = xw[lane * 16 + i];
    cnt += (((w >> 7) & 0xFF) >= 0xC0) ? 1 : 0;
  }
#pragma unroll
  for (int off = 1; off < 64; off <<= 1) cnt += __shfl_xor(cnt, off, 64);
  return cnt >= 32;
}

// ---------------------------------------------------------------------------
// ws layout (u16 elements):
//   WcT [16][128cout][128cin]  @ 0
//   WqT/WkT/WvT/WpT [128][128] @ 262144/278528/294912/311296
//   Kb  [4][1024][128]         @ 327680
//   Vt  [4][128][1024]         @ 851968
// ---------------------------------------------------------------------------
__global__ void prep_kernel(const void* __restrict__ srk, const void* __restrict__ Wq,
                            const void* __restrict__ Wk, const void* __restrict__ Wv,
                            const void* __restrict__ Wp, const void* __restrict__ x,
                            u16* __restrict__ WcT) {
  const int isf32 = detect_isf32((const u16*)x);
  int gid = blockIdx.x * 256 + threadIdx.x;
  if (gid >= 327680) return;
  int cout = (gid >> 7) & 127, cin = gid & 127;
  float v;
  if (gid < 262144) {
    int mat = gid >> 14;  // (r,s) slice of HWIO sr_kernel
    v = ld1(srk, mat * 16384 + cin * 128 + cout, isf32);
  } else {
    int mat = (gid - 262144) >> 14;
    const void* src = (mat == 0) ? Wq : (mat == 1) ? Wk : (mat == 2) ? Wv : Wp;
    v = ld1(src, cin * 128 + cout, isf32);
  }
  WcT[gid] = f2bf(v);
}

// ---------------------------------------------------------------------------
// Conv (stride-4 4x4 'SAME' == patch GEMM) + bias + LayerNorm + fused K/V.
// Grid 256 WGs x 1024 thr (16 waves). Wave w owns conv tap rs=w (K-split 16).
// Partials in 128 KB f32 LDS; reduce = one row per wave; LN via 64-lane
// shuffles; K/V proj: wave w -> (nt=w>>1, K if even / V if odd).
// ---------------------------------------------------------------------------
__launch_bounds__(1024, 4)
__global__ void conv_ln_kv_kernel(const void* __restrict__ x, const u16* __restrict__ wcT,
                                  const void* __restrict__ sr_bias,
                                  const void* __restrict__ gamma,
                                  const void* __restrict__ beta,
                                  const u16* __restrict__ WkT, const u16* __restrict__ WvT,
                                  u16* __restrict__ Kb, u16* __restrict__ Vt) {
  extern __shared__ char cws[];
  float* Racc = (float*)cws;                    // [16][16][128] f32 = 128 KB
  u16* Xs = (u16*)(cws + 16 * 16 * 128 * 4);    // [16][136] bf16
  const int isf32 = detect_isf32((const u16*)x);
  const int tid = threadIdx.x;
  const int wave = tid >> 6, lane = tid & 63;
  const int quad = lane >> 4, l16 = lane & 15;
  const int g = blockIdx.x;  // rows g*16 .. g*16+15

  const int row = g * 16 + l16;
  const int pb = row >> 10, rem = row & 1023, oh = rem >> 5, ow = rem & 31;
  const int xbase = ((pb * 128 + oh * 4) * 128 + ow * 4) * 128;

  f32x4 acc[8];
#pragma unroll
  for (int i = 0; i < 8; ++i) acc[i] = (f32x4){0.f, 0.f, 0.f, 0.f};

  {  // tap rs = wave (r = wave>>2, s = wave&3)
    const int r = wave >> 2, sc = wave & 3;
    short8 a[4];
#pragma unroll
    for (int kc = 0; kc < 4; ++kc)
      a[kc] = ld8(x, xbase + r * 16384 + sc * 128 + kc * 32 + quad * 8, isf32);
#pragma unroll
    for (int nt = 0; nt < 8; ++nt)
#pragma unroll
      for (int kc = 0; kc < 4; ++kc) {
        short8 bw = *(const short8*)(wcT + wave * 16384 + (nt * 16 + l16) * 128 +
                                     kc * 32 + quad * 8);
        acc[nt] = MFMA16(a[kc], bw, acc[nt]);
      }
  }
  // partials -> LDS
#pragma unroll
  for (int nt = 0; nt < 8; ++nt)
#pragma unroll
    for (int rr = 0; rr < 4; ++rr)
      Racc[(wave * 16 + quad * 4 + rr) * 128 + nt * 16 + l16] = acc[nt][rr];
  __syncthreads();

  // reduce 16 wave-slices; wave owns row `wave`, lane owns 2 cols at lane*2
  {
    const int lrow = wave, c0 = lane * 2;
    f32x2 rsum = (f32x2){0.f, 0.f};
#pragma unroll
    for (int w = 0; w < 16; ++w) {
      f32x2 t = *(const f32x2*)&Racc[(w * 16 + lrow) * 128 + c0];
      rsum[0] += t[0];
      rsum[1] += t[1];
    }
    float v0 = rsum[0] + ld1(sr_bias, c0, isf32);
    float v1 = rsum[1] + ld1(sr_bias, c0 + 1, isf32);
    float sum = v0 + v1, sum2 = v0 * v0 + v1 * v1;
#pragma unroll
    for (int off = 1; off < 64; off <<= 1) {
      sum += __shfl_xor(sum, off, 64);
      sum2 += __shfl_xor(sum2, off, 64);
    }
    const float mu = sum * (1.f / 128.f);
    const float var = sum2 * (1.f / 128.f) - mu * mu;
    const float rinv = rsqrtf(fmaxf(var, 0.f) + 1e-6f);
    float y0 = (v0 - mu) * rinv * ld1(gamma, c0, isf32) + ld1(beta, c0, isf32);
    float y1 = (v1 - mu) * rinv * ld1(gamma, c0 + 1, isf32) + ld1(beta, c0 + 1, isf32);
    *(unsigned*)&Xs[lrow * 136 + c0] = pk2(y0, y1);
  }
  __syncthreads();

  // fused K/V projection: wave w -> nt = w>>1; even waves K, odd waves V
  short8 a2[4];
#pragma unroll
  for (int kc = 0; kc < 4; ++kc)
    a2[kc] = *(const short8*)&Xs[l16 * 136 + kc * 32 + quad * 8];
  const u16* Wm = (wave & 1) ? WvT : WkT;
  const int nt = wave >> 1;
  f32x4 a3 = (f32x4){0.f, 0.f, 0.f, 0.f};
#pragma unroll
  for (int kc = 0; kc < 4; ++kc) {
    short8 bm = *(const short8*)(Wm + (nt * 16 + l16) * 128 + kc * 32 + quad * 8);
    a3 = MFMA16(a2[kc], bm, a3);
  }
#pragma unroll
  for (int rr = 0; rr < 4; ++rr) {
    const int rowg = g * 16 + quad * 4 + rr;
    const int b = rowg >> 10, key = rowg & 1023;
    const int c = nt * 16 + l16;
    if (wave & 1)
      Vt[(b * 128 + c) * 1024 + key] = f2bf(a3[rr]);
    else
      Kb[rowg * 128 + c] = f2bf(a3[rr]);
  }
}

// ---------------------------------------------------------------------------
// Fused attention. Grid 512 x 512 thr (8 waves x 16 q-rows = 128 rows/WG).
// EXACT proven 113.3 us structure (V+K cooperatively LDS-staged each chunk,
// LDS 70656 B, launch_bounds(512,4), VGPR 64) with three low-risk additions:
//  * all bf16 packing via v_cvt_pk_bf16_f32 (pk2 asm) — cuts the ~200
//    VALU-ops/chunk of __float2bfloat16 RNE emulation (VALUBusy was 40%)
//  * T1 XCD swizzle (ran R4/R5; FETCH 24.9 -> 18.8 MB)
//  * T5 s_setprio around the PV MFMA cluster (ran R4/R5)
// Occupancy is register-file-bound (~16 waves/CU, unified VGPR+AGPR), so no
// LDS slimming is attempted — round-5 proved it buys nothing.
// ---------------------------------------------------------------------------
__launch_bounds__(512, 4)
__global__ void attn_kernel(const void* __restrict__ x, const u16* __restrict__ WqT,
                            const u16* __restrict__ WpT, const u16* __restrict__ Kb,
                            const u16* __restrict__ Vt, float* __restrict__ out) {
  extern __shared__ u16 lds[];
  u16* Ks = lds;             // [64][136]  8704 el
  u16* Vs = Ks + 64 * 136;   // [128][72]  9216 el
  u16* Pa = Vs + 128 * 72;   // [8][2176]  per-wave scratch
  const int isf32 = detect_isf32((const u16*)x);
  const int tid = threadIdx.x;
  const int wave = tid >> 6, lane = tid & 63;
  const int quad = lane >> 4, l16 = lane & 15;
  const int swz = (blockIdx.x & 7) * 64 + (blockIdx.x >> 3);  // XCD-contiguous
  const int b = swz >> 7;
  const int row0 = (swz & 127) * 128;
  const int wrow = wave * 16;
  u16* Pw = Pa + wave * 2176;

  const float qscale = 0.125f * 1.4426950408889634f;  // dh^-0.5 * log2(e)

  // ---- Q-proj, transposed: D = Q^T[c][q] -> packed b64 -> A-frag reads ----
  short8 qf[2][2];
  {
    short8 xb[4];
#pragma unroll
    for (int kc = 0; kc < 4; ++kc)
      xb[kc] = ld8(x, (b * 16384 + row0 + wrow + l16) * 128 + kc * 32 + quad * 8, isf32);
#pragma unroll
    for (int nt = 0; nt < 8; ++nt) {
      f32x4 qa = (f32x4){0.f, 0.f, 0.f, 0.f};
#pragma unroll
      for (int kc = 0; kc < 4; ++kc) {
        short8 w = *(const short8*)(WqT + (nt * 16 + l16) * 128 + kc * 32 + quad * 8);
        qa = MFMA16(w, xb[kc], qa);  // A=W^T[c][k], B=x[q][k] -> D=Q^T[c][q]
      }
      uint2 pk = {pk2(qa[0] * qscale, qa[1] * qscale), pk2(qa[2] * qscale, qa[3] * qscale)};
      *(uint2*)&Pw[l16 * 136 + nt * 16 + quad * 4] = pk;  // Qst[q][c]
    }
#pragma unroll
    for (int h = 0; h < 2; ++h)
#pragma unroll
      for (int k0 = 0; k0 < 2; ++k0)
        qf[h][k0] = *(const short8*)&Pw[l16 * 136 + h * 64 + k0 * 32 + quad * 8];
  }

  f32x4 o[2][4];
#pragma unroll
  for (int h = 0; h < 2; ++h)
#pragma unroll
    for (int nt = 0; nt < 4; ++nt) o[h][nt] = (f32x4){0.f, 0.f, 0.f, 0.f};
  float l[2] = {0.f, 0.f};

  const int kkey = tid >> 3, kseg = tid & 7;  // K: 64 rows x 8 segs of 16
  const int vc = tid >> 2, vseg = tid & 3;    // V: 128 rows x 4 segs of 16

  for (int ch = 0; ch < 16; ++ch) {
    __syncthreads();
    {  // stage K chunk [64key][128c]
      const uint4* src = (const uint4*)(Kb + (b * 1024 + ch * 64 + kkey) * 128 + kseg * 16);
      uint4* dst = (uint4*)&Ks[kkey * 136 + kseg * 16];
      dst[0] = src[0];
      dst[1] = src[1];
    }
    {  // stage V^T chunk [128c][64key]
      const uint4* src = (const uint4*)(Vt + (b * 128 + vc) * 1024 + ch * 64 + vseg * 16);
      uint4* dst = (uint4*)&Vs[vc * 72 + vseg * 16];
      dst[0] = src[0];
      dst[1] = src[1];
    }
    __syncthreads();
#pragma unroll
    for (int h = 0; h < 2; ++h) {
      // ---- S^T per ct (rows=key, cols=q); exp2; packed P[q][key] ----
#pragma unroll
      for (int ct = 0; ct < 4; ++ct) {
        short8 kf0 = *(const short8*)&Ks[(ct * 16 + l16) * 136 + h * 64 + quad * 8];
        short8 kf1 = *(const short8*)&Ks[(ct * 16 + l16) * 136 + h * 64 + 32 + quad * 8];
        f32x4 s0 = (f32x4){0.f, 0.f, 0.f, 0.f};
        s0 = MFMA16(kf0, qf[h][0], s0);  // A=K[key][d], B=Q[q][d] -> S^T
        s0 = MFMA16(kf1, qf[h][1], s0);
        float p0 = exp2f(s0[0]), p1 = exp2f(s0[1]), p2 = exp2f(s0[2]), p3 = exp2f(s0[3]);
        l[h] += (p0 + p1) + (p2 + p3);
        uint2 pka = {pk2(p0, p1), pk2(p2, p3)};
        *(uint2*)&Pw[l16 * 72 + ct * 16 + quad * 4] = pka;
      }
      // ---- O^T += V^T x P ----
      __builtin_amdgcn_s_setprio(1);
#pragma unroll
      for (int kc = 0; kc < 2; ++kc) {
        short8 pf0 = *(const short8*)&Pw[l16 * 72 + kc * 32 + quad * 8];
#pragma unroll
        for (int nt = 0; nt < 4; ++nt) {
          short8 vf = *(const short8*)&Vs[(h * 64 + nt * 16 + l16) * 72 + kc * 32 + quad * 8];
          o[h][nt] = MFMA16(vf, pf0, o[h][nt]);  // A=V^T[d][key], B=P[q][key]
        }
      }
      __builtin_amdgcn_s_setprio(0);
    }
  }

  // ---- softmax denom (quad-reduce) + normalize O^T in registers ----
#pragma unroll
  for (int h = 0; h < 2; ++h) {
    float t = l[h];
    t += __shfl_xor(t, 16, 64);
    t += __shfl_xor(t, 32, 64);
    const float inv = 1.0f / t;
#pragma unroll
    for (int nt = 0; nt < 4; ++nt)
#pragma unroll
      for (int rr = 0; rr < 4; ++rr) o[h][nt][rr] *= inv;
  }

  // ---- epilogue: packed O^T -> LDS -> A-frags -> @Wproj -> f32 out --
  {
#pragma unroll
    for (int h = 0; h < 2; ++h)
#pragma unroll
      for (int nt = 0; nt < 4; ++nt) {
        uint2 pk = {pk2(o[h][nt][0], o[h][nt][1]), pk2(o[h][nt][2], o[h][nt][3])};
        *(uint2*)&Pw[l16 * 136 + h * 64 + nt * 16 + quad * 4] = pk;  // Ost[q][d]
      }
    short8 of[4];
#pragma unroll
    for (int kc = 0; kc < 4; ++kc)
      of[kc] = *(const short8*)&Pw[l16 * 136 + kc * 32 + quad * 8];
#pragma unroll
    for (int nt = 0; nt < 8; ++nt) {
      f32x4 pa = (f32x4){0.f, 0.f, 0.f, 0.f};
#pragma unroll
      for (int kc = 0; kc < 4; ++kc) {
        short8 w = *(const short8*)(WpT + (nt * 16 + l16) * 128 + kc * 32 + quad * 8);
        pa = MFMA16(of[kc], w, pa);  // A=O[q][d], B=Wp^T[c][d] -> D=[q][c]
      }
#pragma unroll
      for (int rr = 0; rr < 4; ++rr)
        out[(b * 16384 + row0 + wrow + quad * 4 + rr) * 128 + nt * 16 + l16] = pa[rr];
    }
  }
}

// ---------------------------------------------------------------------------
extern "C" void kernel_launch(void* const* d_in, const int* in_sizes, int n_in,
                              void* d_out, int out_size, void* d_ws, size_t ws_size,
                              hipStream_t stream) {
  (void)in_sizes; (void)n_in; (void)out_size; (void)ws_size;
  const void* x = d_in[0];
  const void* Wq = d_in[1];
  const void* Wk = d_in[2];
  const void* Wv = d_in[3];
  const void* Wp = d_in[4];
  const void* srk = d_in[5];
  const void* sbias = d_in[6];
  const void* gamma = d_in[7];
  const void* beta = d_in[8];
  float* out = (float*)d_out;
  u16* ws = (u16*)d_ws;

  u16* WcT = ws;
  u16* WqT = ws + 262144;
  u16* WkT = ws + 278528;
  u16* WvT = ws + 294912;
  u16* WpT = ws + 311296;
  u16* Kb = ws + 327680;
  u16* Vt = ws + 851968;

  prep_kernel<<<dim3(1280), dim3(256), 0, stream>>>(srk, Wq, Wk, Wv, Wp, x, WcT);
  conv_ln_kv_kernel<<<dim3(256), dim3(1024), 16 * 16 * 128 * 4 + 16 * 136 * 2, stream>>>(
      x, WcT, sbias, gamma, beta, WkT, WvT, Kb, Vt);
  attn_kernel<<<dim3(512), dim3(512), (64 * 136 + 128 * 72 + 8 * 2176) * 2, stream>>>(
      x, WqT, WpT, Kb, Vt, out);
}